// Round 11
// baseline (292.628 us; speedup 1.0000x reference)
//
#include <hip/hip_runtime.h>

#define B_ 8
#define C_ 256
#define HW_ 4096
#define E_ 32
#define K_ 8192
#define N_ 32768          // B*H*W
#define NCHUNK 4
#define KC_ (K_ / NCHUNK) // 2048
#define STCODES 128
#define NSTAGE (KC_ / STCODES)   // 16
#define PXB 128           // pixels per score block

#define DECAY_ 0.99f
#define OMD_   0.01f
#define EPS_   1e-5f
#define BETA_  0.25f

// ---- output layout (fp32 elements, concatenated in reference return order) ----
#define O_ZQ   0          // [B,E,H,W] 1048576
#define O_IDX  1048576    // [B,H,W]   32768
#define O_QL   1081344    // scalar    1
#define O_NEMB 1081345    // [K,E]     262144
#define O_NCS  1343489    // [K]       8192
#define O_NW   1351681    // [K,E]     262144

// ---- workspace layout (float offsets); high-water 794626 floats = 3.18 MB (proven r8) ----
// eh/em PRE-SWIZZLED to MFMA-frag order: uint4 chunk (tile t, quad q, c15) at t*64+q*16+c15.
#define WS_EH   0u        // K*E bf16 hi  [0,      131072)
#define WS_EM   131072u   // K*E bf16 lo  [131072, 262144)
#define WS_PACK 262144u   // 4 chunks x N int2 (top1,top2)  [262144, 524288)
#define WS_CNT  524288u   // K counts (zeroed)
#define WS_DW   532480u   // K*E dw (zeroed)
#define WS_SCAL 794624u   // [0]=n sum, [1]=qloss sq (zeroed)
// memset span: WS_CNT .. WS_SCAL+2 = 270338 floats

typedef float f32x4 __attribute__((ext_vector_type(4)));
typedef short s16x8 __attribute__((ext_vector_type(8)));
typedef unsigned long long u64;

__device__ __forceinline__ unsigned short f2bf(float f) {
    unsigned u = __float_as_uint(f);
    u = u + 0x7fffu + ((u >> 16) & 1u);
    return (unsigned short)(u >> 16);
}
__device__ __forceinline__ float bf2f(unsigned short h) {
    return __uint_as_float(((unsigned)h) << 16);
}
__device__ __forceinline__ unsigned ford(float f) {
    unsigned u = __float_as_uint(f);
    return (u & 0x80000000u) ? ~u : (u | 0x80000000u);
}
__device__ __forceinline__ int imax(int a, int b) { return a > b ? a : b; }
__device__ __forceinline__ int imin(int a, int b) { return a < b ? a : b; }

__device__ __forceinline__ void gload_lds16(const void* g, void* l) {
    __builtin_amdgcn_global_load_lds(
        (const __attribute__((address_space(1))) unsigned int*)g,
        (__attribute__((address_space(3))) unsigned int*)l, 16, 0, 0);
}

// ---------------- K0: normalize rows + 2-way bf16 split, stored frag-swizzled ----------------
__global__ __launch_bounds__(256) void k_norm_split(const float* __restrict__ emb,
                                                    uint4* __restrict__ eh16,
                                                    uint4* __restrict__ em16) {
    int k = blockIdx.x * 256 + threadIdx.x;
    if (k >= K_) return;
    const float4* r = (const float4*)(emb + (size_t)k * E_);
    float v[E_];
    float ss = 0.f;
#pragma unroll
    for (int i = 0; i < 8; i++) {
        float4 t = r[i];
        v[i*4+0] = t.x; v[i*4+1] = t.y; v[i*4+2] = t.z; v[i*4+3] = t.w;
        ss += t.x*t.x + t.y*t.y + t.z*t.z + t.w*t.w;
    }
    float inv = 1.0f / fmaxf(sqrtf(ss), 1e-12f);
    unsigned short h1a[E_], h2a[E_];
#pragma unroll
    for (int e = 0; e < E_; e++) {
        float en = v[e] * inv;
        unsigned short h1 = f2bf(en);
        float r1 = en - bf2f(h1);
        h1a[e] = h1; h2a[e] = f2bf(r1);
    }
    int t = k >> 4, c15 = k & 15;
#pragma unroll
    for (int i = 0; i < 4; i++) {   // quad i = k-elements 8i..8i+7
        eh16[t * 64 + i * 16 + c15] = ((uint4*)h1a)[i];
        em16[t * 64 + i * 16 + c15] = ((uint4*)h2a)[i];
    }
}

// ---------------- K1: MFMA score + int-packed per-pixel chunk-local top-2 ----------------
// grid (N/128, NCHUNK), 512 thr (8 waves), 128 pixels, quarter codebook per block.
// LDS: [0,16384) buf0, [16384,32768) buf1; [32768,49152) zbuf (128x32 fp32).
// Phase 1 overlays WqT on [0,32768).
__global__ __launch_bounds__(512) void k_score_mfma(const float* __restrict__ x,
                                                    const float* __restrict__ Wq,
                                                    const float* __restrict__ bq,
                                                    const char* __restrict__ ehb,
                                                    const char* __restrict__ emb_b,
                                                    int2* __restrict__ pk2) {
    __shared__ __align__(16) char smem[49152];
    float* wqt  = (float*)smem;                 // phase 1 only (32 KB)
    float* zbuf = (float*)(smem + 32768);       // 16 KB

    int tid  = threadIdx.x;
    int lane = tid & 63;
    int w    = tid >> 6;
    int chunk = blockIdx.y;

    // ---- phase 1: z for the block's 128 pixels ----
#pragma unroll
    for (int i = 0; i < 16; i++) {
        int g = i * 512 + tid;        // g = e*256 + c  (Wq is [E,C])
        int e = g >> 8;
        int c = g & 255;
        wqt[c * E_ + e] = Wq[g];
    }
    __syncthreads();
    {
        int px = tid & 127, eg = tid >> 7;      // eg 0..3, 8 e's each
        int n0 = blockIdx.x * PXB + px;
        int b  = n0 >> 12, hw = n0 & (HW_ - 1);
        const float* xp = x + (size_t)b * C_ * HW_ + hw;
        float a[8];
#pragma unroll
        for (int j = 0; j < 8; j++) a[j] = 0.f;
#pragma unroll 4
        for (int c = 0; c < C_; c++) {
            float xv = xp[(size_t)c * HW_];
            const float4* wr = (const float4*)(wqt + c * E_ + eg * 8);
            float4 w0 = wr[0], w1 = wr[1];
            a[0] += xv * w0.x; a[1] += xv * w0.y; a[2] += xv * w0.z; a[3] += xv * w0.w;
            a[4] += xv * w1.x; a[5] += xv * w1.y; a[6] += xv * w1.z; a[7] += xv * w1.w;
        }
#pragma unroll
        for (int j = 0; j < 8; j++)
            zbuf[px * E_ + eg * 8 + j] = a[j] + bq[eg * 8 + j];
    }
    __syncthreads();

    // ---- A fragments: z * 2^27, 2-way bf16 split. A[m=lane&15][k=(lane>>4)*8+j] ----
    s16x8 a1, a2;
    {
        int ploc = w * 16 + (lane & 15);
        int e0   = (lane >> 4) * 8;
#pragma unroll
        for (int j = 0; j < 8; j++) {
            float zv = zbuf[ploc * E_ + e0 + j] * 134217728.0f;  // 2^27 (exact)
            unsigned short h1 = f2bf(zv);
            float r1 = zv - bf2f(h1);
            a1[j] = (short)h1; a2[j] = (short)f2bf(r1);
        }
    }
    __syncthreads();   // zbuf reads done; phase-2 staging may start

    // staging sources: this thread loads one 16B chunk per plane per stage
    const char* srcA = ehb   + (size_t)chunk * (KC_ * 64) + tid * 16;
    const char* srcB = emb_b + (size_t)chunk * (KC_ * 64) + tid * 16;

    // prologue: stage 0 -> buf0
    gload_lds16(srcA, smem + tid * 16);
    gload_lds16(srcB, smem + 8192 + tid * 16);
    __syncthreads();

    int rbase = 8191 - chunk * KC_ - (lane & 15);
    int bq1[4], bq2[4];
#pragma unroll
    for (int j = 0; j < 4; j++) { bq1[j] = (int)0x80000000; bq2[j] = (int)0x80000000; }
    f32x4 zero4 = {0.f, 0.f, 0.f, 0.f};

    for (int st = 0; st < NSTAGE; st++) {
        if (st + 1 < NSTAGE) {
            char* dst = smem + ((st + 1) & 1) * 16384;
            gload_lds16(srcA + (size_t)(st + 1) * 8192, dst + tid * 16);
            gload_lds16(srcB + (size_t)(st + 1) * 8192, dst + 8192 + tid * 16);
        }
        const char* cur = smem + (st & 1) * 16384;
        int rst = rbase - st * 128;

#pragma unroll
        for (int ct = 0; ct < 8; ct += 2) {
            s16x8 b1a = ((const s16x8*)(cur +        ct * 1024))[lane];
            s16x8 b2a = ((const s16x8*)(cur + 8192 + ct * 1024))[lane];
            s16x8 b1b = ((const s16x8*)(cur +        ct * 1024 + 1024))[lane];
            s16x8 b2b = ((const s16x8*)(cur + 8192 + ct * 1024 + 1024))[lane];
            f32x4 acc0 = __builtin_amdgcn_mfma_f32_16x16x32_bf16(a1, b1a, zero4, 0, 0, 0);
            f32x4 acc1 = __builtin_amdgcn_mfma_f32_16x16x32_bf16(a1, b1b, zero4, 0, 0, 0);
            acc0 = __builtin_amdgcn_mfma_f32_16x16x32_bf16(a1, b2a, acc0, 0, 0, 0);
            acc1 = __builtin_amdgcn_mfma_f32_16x16x32_bf16(a1, b2b, acc1, 0, 0, 0);
            acc0 = __builtin_amdgcn_mfma_f32_16x16x32_bf16(a2, b1a, acc0, 0, 0, 0);
            acc1 = __builtin_amdgcn_mfma_f32_16x16x32_bf16(a2, b1b, acc1, 0, 0, 0);
            int rA = rst - ct * 16;
            int rB = rA - 16;
#pragma unroll
            for (int j = 0; j < 4; j++) {
                int va = ((int)acc0[j] & (int)0xFFFFE000) | rA;  // v_cvt + v_and_or
                int vb = ((int)acc1[j] & (int)0xFFFFE000) | rB;
                int hi = imax(va, vb), lo = imin(va, vb);
                int m  = imin(bq1[j], hi);
                bq1[j] = imax(bq1[j], hi);
                bq2[j] = imax(imax(bq2[j], lo), m);
            }
        }
        __syncthreads();
    }

    // butterfly top-2 merge across 16-lane code groups
#pragma unroll
    for (int off = 1; off < 16; off <<= 1) {
#pragma unroll
        for (int j = 0; j < 4; j++) {
            int o1 = __shfl_xor(bq1[j], off, 64);
            int o2 = __shfl_xor(bq2[j], off, 64);
            int m  = imin(bq1[j], o1);
            bq1[j] = imax(bq1[j], o1);
            bq2[j] = imax(imax(bq2[j], o2), m);
        }
    }
    if ((lane & 15) == 0) {
        int rowbase = blockIdx.x * PXB + w * 16 + (lane >> 4) * 4;
#pragma unroll
        for (int j = 0; j < 4; j++)
            pk2[(size_t)chunk * N_ + rowbase + j] = make_int2(bq1[j], bq2[j]);
    }
}

// exact round-4-order rescore of one candidate code against z[32]
__device__ __forceinline__ float rescore(const float* __restrict__ emb, int k,
                                         const float* zrow) {
    const float4* r = (const float4*)(emb + (size_t)k * E_);
    float4 v[8];
    float ss = 0.f;
#pragma unroll
    for (int i = 0; i < 8; i++) {
        v[i] = r[i];
        ss += v[i].x * v[i].x + v[i].y * v[i].y + v[i].z * v[i].z + v[i].w * v[i].w;
    }
    float inv = 1.0f / fmaxf(sqrtf(ss), 1e-12f);
    const float4* zp = (const float4*)zrow;
    float sx = 0.f, sy = 0.f, sz = 0.f, sw = 0.f;
#pragma unroll
    for (int i = 0; i < 8; i++) {
        float4 e4 = make_float4(v[i].x * inv, v[i].y * inv, v[i].z * inv, v[i].w * inv);
        float4 zr = zp[i];
        sx += zr.x * e4.x; sy += zr.y * e4.y;
        sz += zr.z * e4.z; sw += zr.w * e4.w;
    }
    return (sx + sy) + (sz + sw);
}

// ---------------- K2: recompute z, rescore 8 candidates (parallel), gather/scatter ----------------
// 512 threads (8 waves), 64 pixels.
__global__ __launch_bounds__(512) void k_scatter(const float* __restrict__ x,
                                                 const float* __restrict__ Wq,
                                                 const float* __restrict__ bq,
                                                 const int2* __restrict__ pk2,
                                                 const float* __restrict__ emb,
                                                 float* __restrict__ out_zq,
                                                 float* __restrict__ out_idx,
                                                 float* __restrict__ dw,
                                                 float* __restrict__ cnt,
                                                 float* __restrict__ scal) {
    __shared__ float wqt[C_ * E_];     // 32 KB
    __shared__ float zbuf[64 * E_];    // 8 KB
    __shared__ int   idxs_s[64];
    __shared__ float red[8];
    int tid = threadIdx.x;
#pragma unroll
    for (int i = 0; i < 16; i++) {
        int g = i * 512 + tid;
        int e = g >> 8;
        int c = g & 255;
        wqt[c * E_ + e] = Wq[g];
    }
    __syncthreads();

    int lp = tid & 63, eg = tid >> 6;   // eg 0..7, 4 e's each
    int n  = blockIdx.x * 64 + lp;
    int b  = n >> 12, hw = n & (HW_ - 1);
    const float* xp = x + (size_t)b * C_ * HW_ + hw;

    float a[4] = {0.f, 0.f, 0.f, 0.f};
#pragma unroll 8
    for (int c = 0; c < C_; c++) {
        float xv = xp[(size_t)c * HW_];
        float4 w0 = *(const float4*)(wqt + c * E_ + eg * 4);
        a[0] += xv * w0.x; a[1] += xv * w0.y; a[2] += xv * w0.z; a[3] += xv * w0.w;
    }
#pragma unroll
    for (int j = 0; j < 4; j++) a[j] += bq[eg * 4 + j];
#pragma unroll
    for (int j = 0; j < 4; j++) zbuf[lp * E_ + eg * 4 + j] = a[j];
    __syncthreads();

    {   // 8 candidates per pixel: (chunk 0..3) x (top1, top2)
        int p = tid >> 3, c8 = tid & 7;
        int nn = blockIdx.x * 64 + p;
        int2 c2 = pk2[(size_t)(c8 >> 1) * N_ + nn];
        int raw = (c8 & 1) ? c2.y : c2.x;
        int k = 8191 - (raw & 0x1fff);
        k = k < 0 ? 0 : (k > K_ - 1 ? K_ - 1 : k);
        float s = rescore(emb, k, zbuf + p * E_);
        u64 pkd = ((u64)ford(s) << 32) | (unsigned)(K_ - 1 - k);  // ties -> lowest idx
        u64 o = __shfl_xor(pkd, 1, 64); pkd = pkd > o ? pkd : o;
        o = __shfl_xor(pkd, 2, 64);     pkd = pkd > o ? pkd : o;
        o = __shfl_xor(pkd, 4, 64);     pkd = pkd > o ? pkd : o;
        if (c8 == 0) {
            int bi = K_ - 1 - (int)(unsigned)(pkd & 0xffffffffu);
            idxs_s[p] = bi;
            out_idx[nn] = (float)bi;
        }
    }
    __syncthreads();

    int idx = idxs_s[lp];
    const float* er = emb + (size_t)idx * E_ + eg * 4;
    float* o = out_zq + (size_t)b * E_ * HW_ + (size_t)(eg * 4) * HW_ + hw;

    float sq = 0.f;
#pragma unroll
    for (int j = 0; j < 4; j++) {
        float zv = a[j];
        float qf = er[j];
        float d = qf - zv;
        sq += d * d;
        o[(size_t)j * HW_] = qf;
        atomicAdd(dw + (size_t)idx * E_ + eg * 4 + j, zv);
    }
    if (eg == 0) atomicAdd(cnt + idx, 1.0f);

#pragma unroll
    for (int off = 32; off > 0; off >>= 1) sq += __shfl_down(sq, off);
    int lane = tid & 63, wid = tid >> 6;
    if (lane == 0) red[wid] = sq;
    __syncthreads();
    if (tid == 0) {
        float t = 0.f;
#pragma unroll
        for (int i = 0; i < 8; i++) t += red[i];
        atomicAdd(scal + 1, t);
    }
}

// ---------------- K3: EMA cluster size + n reduction ----------------
__global__ __launch_bounds__(256) void k_ema_cs(const float* __restrict__ cs,
                                                const float* __restrict__ cnt,
                                                float* __restrict__ out_ncs,
                                                float* __restrict__ scal) {
    int tid = threadIdx.x;
    int k = blockIdx.x * 256 + tid;
    float v = DECAY_ * cs[k] + OMD_ * cnt[k];
    out_ncs[k] = v;

    float s = v;
#pragma unroll
    for (int off = 32; off > 0; off >>= 1) s += __shfl_down(s, off);
    __shared__ float red[4];
    int lane = tid & 63, wid = tid >> 6;
    if (lane == 0) red[wid] = s;
    __syncthreads();
    if (tid == 0) atomicAdd(scal + 0, red[0] + red[1] + red[2] + red[3]);
}

// ---------------- K4: new_w + smoothed division + qloss ----------------
__global__ __launch_bounds__(256) void k_final(const float* __restrict__ ew,
                                               const float* __restrict__ dw,
                                               const float* __restrict__ cs,
                                               const float* __restrict__ cnt,
                                               const float* __restrict__ scal,
                                               float* __restrict__ out_nw,
                                               float* __restrict__ out_nemb,
                                               float* __restrict__ out_ql) {
    int j = blockIdx.x * 256 + threadIdx.x;  // < K_*E_
    float v = DECAY_ * ew[j] + OMD_ * dw[j];
    out_nw[j] = v;
    float nsum = scal[0];
    int k = j >> 5;
    float csk = DECAY_ * cs[k] + OMD_ * cnt[k];
    float denom = (csk + EPS_) / (nsum + (float)K_ * EPS_) * nsum;
    out_nemb[j] = v / denom;
    if (j == 0) {
        out_ql[0] = BETA_ * scal[1] / (float)(B_ * E_ * HW_);
    }
}

extern "C" void kernel_launch(void* const* d_in, const int* in_sizes, int n_in,
                              void* d_out, int out_size, void* d_ws, size_t ws_size,
                              hipStream_t stream) {
    const float* x   = (const float*)d_in[0];
    const float* Wq  = (const float*)d_in[1];
    const float* bq  = (const float*)d_in[2];
    const float* emb = (const float*)d_in[3];
    const float* cs  = (const float*)d_in[4];
    const float* ew  = (const float*)d_in[5];
    float* out = (float*)d_out;
    float* ws  = (float*)d_ws;

    hipMemsetAsync(ws + WS_CNT, 0, (size_t)270338 * sizeof(float), stream);

    k_norm_split<<<K_ / 256, 256, 0, stream>>>(emb,
        (uint4*)(ws + WS_EH), (uint4*)(ws + WS_EM));
    k_score_mfma<<<dim3(N_ / PXB, NCHUNK), 512, 0, stream>>>(x, Wq, bq,
        (const char*)(ws + WS_EH), (const char*)(ws + WS_EM),
        (int2*)(ws + WS_PACK));
    k_scatter<<<N_ / 64, 512, 0, stream>>>(x, Wq, bq,
        (const int2*)(ws + WS_PACK), emb,
        out + O_ZQ, out + O_IDX, ws + WS_DW, ws + WS_CNT, ws + WS_SCAL);
    k_ema_cs<<<K_ / 256, 256, 0, stream>>>(cs, ws + WS_CNT, out + O_NCS, ws + WS_SCAL);
    k_final<<<(K_ * E_) / 256, 256, 0, stream>>>(ew, ws + WS_DW, cs, ws + WS_CNT,
                                                 ws + WS_SCAL, out + O_NW,
                                                 out + O_NEMB, out + O_QL);
}

// Round 12
// 267.102 us; speedup vs baseline: 1.0956x; 1.0956x over previous
//
#include <hip/hip_runtime.h>

#define B_ 8
#define C_ 256
#define HW_ 4096
#define E_ 32
#define K_ 8192
#define N_ 32768          // B*H*W
#define NCHUNK 2
#define KC_ (K_ / NCHUNK) // 4096
#define NSTAGE (KC_ / 128)   // 32

#define DECAY_ 0.99f
#define OMD_   0.01f
#define EPS_   1e-5f
#define BETA_  0.25f

// ---- output layout (fp32 elements, concatenated in reference return order) ----
#define O_ZQ   0          // [B,E,H,W] 1048576
#define O_IDX  1048576    // [B,H,W]   32768
#define O_QL   1081344    // scalar    1
#define O_NEMB 1081345    // [K,E]     262144
#define O_NCS  1343489    // [K]       8192
#define O_NW   1351681    // [K,E]     262144

// ---- workspace layout (float offsets); high-water 1712130 floats = 6.85 MB ----
// eh/em PRE-SWIZZLED to MFMA-frag order: uint4 chunk (tile t, quad q, c15) at t*64+q*16+c15.
#define WS_EH   0u        // K*E bf16 hi   [0,       131072)
#define WS_EM   131072u   // K*E bf16 lo   [131072,  262144)
#define WS_Z    262144u   // N*E fp32 z    [262144, 1310720)
#define WS_PACK 1310720u  // 2 chunks x N int2 (top1,top2) [1310720, 1441792)
#define WS_CNT  1441792u  // K counts (zeroed)
#define WS_DW   1449984u  // K*E dw (zeroed)
#define WS_SCAL 1712128u  // [0]=n sum, [1]=qloss sq (zeroed)
// memset span: WS_CNT .. WS_SCAL+2 = 270338 floats

typedef float f32x4 __attribute__((ext_vector_type(4)));
typedef short s16x8 __attribute__((ext_vector_type(8)));
typedef unsigned long long u64;

__device__ __forceinline__ unsigned short f2bf(float f) {
    unsigned u = __float_as_uint(f);
    u = u + 0x7fffu + ((u >> 16) & 1u);
    return (unsigned short)(u >> 16);
}
__device__ __forceinline__ float bf2f(unsigned short h) {
    return __uint_as_float(((unsigned)h) << 16);
}
__device__ __forceinline__ unsigned ford(float f) {
    unsigned u = __float_as_uint(f);
    return (u & 0x80000000u) ? ~u : (u | 0x80000000u);
}
__device__ __forceinline__ int imax(int a, int b) { return a > b ? a : b; }
__device__ __forceinline__ int imin(int a, int b) { return a < b ? a : b; }

__device__ __forceinline__ void gload_lds16(const void* g, void* l) {
    __builtin_amdgcn_global_load_lds(
        (const __attribute__((address_space(1))) unsigned int*)g,
        (__attribute__((address_space(3))) unsigned int*)l, 16, 0, 0);
}

// ---------------- K0: normalize rows + 2-way bf16 split, stored frag-swizzled ----------------
__global__ __launch_bounds__(256) void k_norm_split(const float* __restrict__ emb,
                                                    uint4* __restrict__ eh16,
                                                    uint4* __restrict__ em16) {
    int k = blockIdx.x * 256 + threadIdx.x;
    if (k >= K_) return;
    const float4* r = (const float4*)(emb + (size_t)k * E_);
    float v[E_];
    float ss = 0.f;
#pragma unroll
    for (int i = 0; i < 8; i++) {
        float4 t = r[i];
        v[i*4+0] = t.x; v[i*4+1] = t.y; v[i*4+2] = t.z; v[i*4+3] = t.w;
        ss += t.x*t.x + t.y*t.y + t.z*t.z + t.w*t.w;
    }
    float inv = 1.0f / fmaxf(sqrtf(ss), 1e-12f);
    unsigned short h1a[E_], h2a[E_];
#pragma unroll
    for (int e = 0; e < E_; e++) {
        float en = v[e] * inv;
        unsigned short h1 = f2bf(en);
        float r1 = en - bf2f(h1);
        h1a[e] = h1; h2a[e] = f2bf(r1);
    }
    int t = k >> 4, c15 = k & 15;
#pragma unroll
    for (int i = 0; i < 4; i++) {   // quad i = k-elements 8i..8i+7
        eh16[t * 64 + i * 16 + c15] = ((uint4*)h1a)[i];
        em16[t * 64 + i * 16 + c15] = ((uint4*)h2a)[i];
    }
}

// ---------------- K1: MFMA score + int-packed per-pixel chunk-local top-2 ----------------
// grid (N/64, NCHUNK), 256 thr (4 waves), 64 pixels, half codebook per block.
// LDS: [0,16384) buf0, [16384,32768) buf1 (stage: 8KB hi + 8KB lo); [32768,40960) zbuf.
// Phase 1 overlays WqT on [0,32768). chunk-0 blocks also write z to ws.
__global__ __launch_bounds__(256) void k_score_mfma(const float* __restrict__ x,
                                                    const float* __restrict__ Wq,
                                                    const float* __restrict__ bq,
                                                    const char* __restrict__ ehb,
                                                    const char* __restrict__ emb_b,
                                                    float* __restrict__ zout,
                                                    int2* __restrict__ pk2) {
    __shared__ __align__(16) char smem[40960];
    float* wqt  = (float*)smem;                 // phase 1 only (32 KB)
    float* zbuf = (float*)(smem + 32768);

    int tid  = threadIdx.x;
    int lane = tid & 63;
    int w    = tid >> 6;
    int chunk = blockIdx.y;

    // ---- phase 1: z for the block's 64 pixels ----
#pragma unroll
    for (int i = 0; i < 32; i++) {
        int g = i * 256 + tid;        // g = e*256 + c  (Wq is [E,C])
        int e = g >> 8;
        int c = g & 255;
        wqt[c * E_ + e] = Wq[g];
    }
    __syncthreads();
    {
        int lp = tid & 63, eg = tid >> 6;
        int n0 = blockIdx.x * 64 + lp;
        int b  = n0 >> 12, hw = n0 & (HW_ - 1);
        const float* xp = x + (size_t)b * C_ * HW_ + hw;
        float a[8];
#pragma unroll
        for (int j = 0; j < 8; j++) a[j] = 0.f;
#pragma unroll 4
        for (int c = 0; c < C_; c++) {
            float xv = xp[(size_t)c * HW_];
            const float4* wr = (const float4*)(wqt + c * E_ + eg * 8);
            float4 w0 = wr[0], w1 = wr[1];
            a[0] += xv * w0.x; a[1] += xv * w0.y; a[2] += xv * w0.z; a[3] += xv * w0.w;
            a[4] += xv * w1.x; a[5] += xv * w1.y; a[6] += xv * w1.z; a[7] += xv * w1.w;
        }
        float4 o0 = make_float4(a[0] + bq[eg*8+0], a[1] + bq[eg*8+1],
                                a[2] + bq[eg*8+2], a[3] + bq[eg*8+3]);
        float4 o1 = make_float4(a[4] + bq[eg*8+4], a[5] + bq[eg*8+5],
                                a[6] + bq[eg*8+6], a[7] + bq[eg*8+7]);
        float4* zo = (float4*)(zbuf + lp * E_ + eg * 8);
        zo[0] = o0; zo[1] = o1;
        if (chunk == 0) {            // cache z for the scatter kernel
            float4* zg = (float4*)(zout + (size_t)n0 * E_ + eg * 8);
            zg[0] = o0; zg[1] = o1;
        }
    }
    __syncthreads();

    // ---- A fragments: z * 2^27 (exact), 2-way bf16 split. A[m=lane&15][k=(lane>>4)*8+j] ----
    s16x8 a1, a2;
    {
        int ploc = w * 16 + (lane & 15);
        int e0   = (lane >> 4) * 8;
#pragma unroll
        for (int j = 0; j < 8; j++) {
            float zv = zbuf[ploc * E_ + e0 + j] * 134217728.0f;  // 2^27
            unsigned short h1 = f2bf(zv);
            float r1 = zv - bf2f(h1);
            a1[j] = (short)h1; a2[j] = (short)f2bf(r1);
        }
    }

    // staging sources (pre-swizzled planes are stage-linear)
    const char* srcp[4];
#pragma unroll
    for (int i = 0; i < 4; i++) {
        int d = i * 256 + tid;
        int pl = d >> 9, dd = d & 511;
        srcp[i] = (pl ? emb_b : ehb) + (size_t)chunk * (KC_ * 64) + dd * 16;
    }

    // prologue: stage 0 -> buf0
#pragma unroll
    for (int i = 0; i < 4; i++)
        gload_lds16(srcp[i], smem + (i * 256 + tid) * 16);
    __syncthreads();

    int rbase = 8191 - chunk * KC_ - (lane & 15);
    int bq1[4], bq2[4];
#pragma unroll
    for (int j = 0; j < 4; j++) { bq1[j] = (int)0x80000000; bq2[j] = (int)0x80000000; }
    f32x4 zero4 = {0.f, 0.f, 0.f, 0.f};

    for (int st = 0; st < NSTAGE; st++) {
        if (st + 1 < NSTAGE) {
            char* dst = smem + ((st + 1) & 1) * 16384;
#pragma unroll
            for (int i = 0; i < 4; i++)
                gload_lds16(srcp[i] + (size_t)(st + 1) * 8192, dst + (i * 256 + tid) * 16);
        }
        const char* cur = smem + (st & 1) * 16384;
        int rst = rbase - st * 128;

#pragma unroll
        for (int ct = 0; ct < 8; ct += 2) {
            s16x8 b1a = ((const s16x8*)(cur +        ct * 1024))[lane];
            s16x8 b2a = ((const s16x8*)(cur + 8192 + ct * 1024))[lane];
            s16x8 b1b = ((const s16x8*)(cur +        ct * 1024 + 1024))[lane];
            s16x8 b2b = ((const s16x8*)(cur + 8192 + ct * 1024 + 1024))[lane];
            f32x4 acc0 = __builtin_amdgcn_mfma_f32_16x16x32_bf16(a1, b1a, zero4, 0, 0, 0);
            f32x4 acc1 = __builtin_amdgcn_mfma_f32_16x16x32_bf16(a1, b1b, zero4, 0, 0, 0);
            acc0 = __builtin_amdgcn_mfma_f32_16x16x32_bf16(a1, b2a, acc0, 0, 0, 0);
            acc1 = __builtin_amdgcn_mfma_f32_16x16x32_bf16(a1, b2b, acc1, 0, 0, 0);
            acc0 = __builtin_amdgcn_mfma_f32_16x16x32_bf16(a2, b1a, acc0, 0, 0, 0);
            acc1 = __builtin_amdgcn_mfma_f32_16x16x32_bf16(a2, b1b, acc1, 0, 0, 0);
            int rA = rst - ct * 16;
            int rB = rA - 16;
#pragma unroll
            for (int j = 0; j < 4; j++) {
                int va = ((int)acc0[j] & (int)0xFFFFE000) | rA;
                int vb = ((int)acc1[j] & (int)0xFFFFE000) | rB;
                int hi = imax(va, vb), lo = imin(va, vb);
                int m  = imin(bq1[j], hi);
                bq1[j] = imax(bq1[j], hi);
                bq2[j] = imax(imax(bq2[j], lo), m);
            }
        }
        __syncthreads();
    }

    // butterfly top-2 merge across 16-lane code groups
#pragma unroll
    for (int off = 1; off < 16; off <<= 1) {
#pragma unroll
        for (int j = 0; j < 4; j++) {
            int o1 = __shfl_xor(bq1[j], off, 64);
            int o2 = __shfl_xor(bq2[j], off, 64);
            int m  = imin(bq1[j], o1);
            bq1[j] = imax(bq1[j], o1);
            bq2[j] = imax(imax(bq2[j], o2), m);
        }
    }
    if ((lane & 15) == 0) {
        int rowbase = blockIdx.x * 64 + w * 16 + (lane >> 4) * 4;
#pragma unroll
        for (int j = 0; j < 4; j++)
            pk2[(size_t)chunk * N_ + rowbase + j] = make_int2(bq1[j], bq2[j]);
    }
}

// exact rescore of one candidate code against z[32] (same order as r8-r11: 0 flips)
__device__ __forceinline__ float rescore(const float* __restrict__ emb, int k,
                                         const float* zrow) {
    const float4* r = (const float4*)(emb + (size_t)k * E_);
    float4 v[8];
    float ss = 0.f;
#pragma unroll
    for (int i = 0; i < 8; i++) {
        v[i] = r[i];
        ss += v[i].x * v[i].x + v[i].y * v[i].y + v[i].z * v[i].z + v[i].w * v[i].w;
    }
    float inv = 1.0f / fmaxf(sqrtf(ss), 1e-12f);
    const float4* zp = (const float4*)zrow;
    float sx = 0.f, sy = 0.f, sz = 0.f, sw = 0.f;
#pragma unroll
    for (int i = 0; i < 8; i++) {
        float4 e4 = make_float4(v[i].x * inv, v[i].y * inv, v[i].z * inv, v[i].w * inv);
        float4 zr = zp[i];
        sx += zr.x * e4.x; sy += zr.y * e4.y;
        sz += zr.z * e4.z; sw += zr.w * e4.w;
    }
    return (sx + sy) + (sz + sw);
}

// ---------------- K2: load cached z, rescore 4 candidates, gather/scatter ----------------
// 256 threads, 64 pixels. No Wq/x work at all.
__global__ __launch_bounds__(256) void k_scatter(const float* __restrict__ zws,
                                                 const int2* __restrict__ pk2,
                                                 const float* __restrict__ emb,
                                                 float* __restrict__ out_zq,
                                                 float* __restrict__ out_idx,
                                                 float* __restrict__ dw,
                                                 float* __restrict__ cnt,
                                                 float* __restrict__ scal) {
    __shared__ float zbuf[64 * E_];    // 8 KB
    __shared__ int   idxs_s[64];
    __shared__ float red[4];
    int tid = threadIdx.x;

    // coalesced z load: 2048 floats = 512 float4
    const float4* zsrc = (const float4*)(zws + (size_t)blockIdx.x * 64 * E_);
    float4* zdst = (float4*)zbuf;
    zdst[tid]       = zsrc[tid];
    zdst[tid + 256] = zsrc[tid + 256];
    __syncthreads();

    {   // 4 candidates per pixel: (chunk 0..1) x (top1, top2)
        int p = tid >> 2, c4 = tid & 3;
        int nn = blockIdx.x * 64 + p;
        int2 c2 = pk2[(size_t)(c4 >> 1) * N_ + nn];
        int raw = (c4 & 1) ? c2.y : c2.x;
        int k = 8191 - (raw & 0x1fff);
        k = k < 0 ? 0 : (k > K_ - 1 ? K_ - 1 : k);
        float s = rescore(emb, k, zbuf + p * E_);
        u64 pkd = ((u64)ford(s) << 32) | (unsigned)(K_ - 1 - k);  // ties -> lowest idx
        u64 o = __shfl_xor(pkd, 1, 64); pkd = pkd > o ? pkd : o;
        o = __shfl_xor(pkd, 2, 64);     pkd = pkd > o ? pkd : o;
        if (c4 == 0) {
            int bi = K_ - 1 - (int)(unsigned)(pkd & 0xffffffffu);
            idxs_s[p] = bi;
            out_idx[nn] = (float)bi;
        }
    }
    __syncthreads();

    int lp = tid & 63, eg = tid >> 6;     // eg 0..3, 8 e's each
    int n  = blockIdx.x * 64 + lp;
    int b  = n >> 12, hw = n & (HW_ - 1);
    int idx = idxs_s[lp];
    const float* er = emb + (size_t)idx * E_ + eg * 8;
    float* o = out_zq + (size_t)b * E_ * HW_ + (size_t)(eg * 8) * HW_ + hw;

    float sq = 0.f;
#pragma unroll
    for (int j = 0; j < 8; j++) {
        float zv = zbuf[lp * E_ + eg * 8 + j];
        float qf = er[j];
        float d = qf - zv;
        sq += d * d;
        o[(size_t)j * HW_] = qf;
        atomicAdd(dw + (size_t)idx * E_ + eg * 8 + j, zv);
    }
    if (eg == 0) atomicAdd(cnt + idx, 1.0f);

#pragma unroll
    for (int off = 32; off > 0; off >>= 1) sq += __shfl_down(sq, off);
    int lane = tid & 63, wid = tid >> 6;
    if (lane == 0) red[wid] = sq;
    __syncthreads();
    if (tid == 0) atomicAdd(scal + 1, red[0] + red[1] + red[2] + red[3]);
}

// ---------------- K3: EMA cluster size + n reduction ----------------
__global__ __launch_bounds__(256) void k_ema_cs(const float* __restrict__ cs,
                                                const float* __restrict__ cnt,
                                                float* __restrict__ out_ncs,
                                                float* __restrict__ scal) {
    int tid = threadIdx.x;
    int k = blockIdx.x * 256 + tid;
    float v = DECAY_ * cs[k] + OMD_ * cnt[k];
    out_ncs[k] = v;

    float s = v;
#pragma unroll
    for (int off = 32; off > 0; off >>= 1) s += __shfl_down(s, off);
    __shared__ float red[4];
    int lane = tid & 63, wid = tid >> 6;
    if (lane == 0) red[wid] = s;
    __syncthreads();
    if (tid == 0) atomicAdd(scal + 0, red[0] + red[1] + red[2] + red[3]);
}

// ---------------- K4: new_w + smoothed division + qloss ----------------
__global__ __launch_bounds__(256) void k_final(const float* __restrict__ ew,
                                               const float* __restrict__ dw,
                                               const float* __restrict__ cs,
                                               const float* __restrict__ cnt,
                                               const float* __restrict__ scal,
                                               float* __restrict__ out_nw,
                                               float* __restrict__ out_nemb,
                                               float* __restrict__ out_ql) {
    int j = blockIdx.x * 256 + threadIdx.x;  // < K_*E_
    float v = DECAY_ * ew[j] + OMD_ * dw[j];
    out_nw[j] = v;
    float nsum = scal[0];
    int k = j >> 5;
    float csk = DECAY_ * cs[k] + OMD_ * cnt[k];
    float denom = (csk + EPS_) / (nsum + (float)K_ * EPS_) * nsum;
    out_nemb[j] = v / denom;
    if (j == 0) {
        out_ql[0] = BETA_ * scal[1] / (float)(B_ * E_ * HW_);
    }
}

extern "C" void kernel_launch(void* const* d_in, const int* in_sizes, int n_in,
                              void* d_out, int out_size, void* d_ws, size_t ws_size,
                              hipStream_t stream) {
    const float* x   = (const float*)d_in[0];
    const float* Wq  = (const float*)d_in[1];
    const float* bq  = (const float*)d_in[2];
    const float* emb = (const float*)d_in[3];
    const float* cs  = (const float*)d_in[4];
    const float* ew  = (const float*)d_in[5];
    float* out = (float*)d_out;
    float* ws  = (float*)d_ws;

    hipMemsetAsync(ws + WS_CNT, 0, (size_t)270338 * sizeof(float), stream);

    k_norm_split<<<K_ / 256, 256, 0, stream>>>(emb,
        (uint4*)(ws + WS_EH), (uint4*)(ws + WS_EM));
    k_score_mfma<<<dim3(N_ / 64, NCHUNK), 256, 0, stream>>>(x, Wq, bq,
        (const char*)(ws + WS_EH), (const char*)(ws + WS_EM),
        ws + WS_Z, (int2*)(ws + WS_PACK));
    k_scatter<<<N_ / 64, 256, 0, stream>>>(ws + WS_Z,
        (const int2*)(ws + WS_PACK), emb,
        out + O_ZQ, out + O_IDX, ws + WS_DW, ws + WS_CNT, ws + WS_SCAL);
    k_ema_cs<<<K_ / 256, 256, 0, stream>>>(cs, ws + WS_CNT, out + O_NCS, ws + WS_SCAL);
    k_final<<<(K_ * E_) / 256, 256, 0, stream>>>(ew, ws + WS_DW, cs, ws + WS_CNT,
                                                 ws + WS_SCAL, out + O_NW,
                                                 out + O_NEMB, out + O_QL);
}